// Round 8
// baseline (100.491 us; speedup 1.0000x reference)
//
#include <hip/hip_runtime.h>
#include <hip/hip_bf16.h>

typedef short bf16x8 __attribute__((ext_vector_type(8)));
typedef float f32x4 __attribute__((ext_vector_type(4)));
typedef unsigned short u16x8 __attribute__((ext_vector_type(8)));

#define GLOAD(gp, lp)                                                          \
    __builtin_amdgcn_global_load_lds(                                          \
        (const __attribute__((address_space(1))) void*)(gp),                   \
        (__attribute__((address_space(3))) void*)(lp), 16, 0, 0)

#define PIN8(v)                                                                \
    asm volatile("" ::"v"((v)[0]), "v"((v)[1]), "v"((v)[2]), "v"((v)[3]),      \
                 "v"((v)[4]), "v"((v)[5]), "v"((v)[6]), "v"((v)[7]))

// Problem sizes: B=16, C=256, HW=4096 (64*64)
static constexpr int kB = 16;
static constexpr int kC = 256;
static constexpr int kHW = 4096;

// Workspace layout (float offsets)
static constexpr int OFF_INVC_T = 0;        // 65536 floats
static constexpr int OFF_INVC_S = 65536;    // 65536 floats
static constexpr int OFF_INVD_T = 131072;   // 4096 floats
static constexpr int OFF_INVD_S = 135168;   // 4096 floats
static constexpr int OFF_EXPS   = 139264;   // 16 floats
static constexpr int OFF_POSS   = 139280;   // 16 floats
static constexpr size_t OFF_U_BYTES = 139296ull * 4ull;       // bf16: raw xb, then u in place
static constexpr size_t U_ELEMS = (size_t)kB * kC * kHW;      // 16777216 per tensor
// psim area after u. Aliased earlier by colnorm partials (64 x 65536 floats
// = 16 MB), consumed by invc_fin_k, then overwritten by gemm partial tiles.
static constexpr size_t OFF_PSIM = 139296ull + 16777216ull;   // float offset

__device__ __forceinline__ unsigned short f2bf(float f) {
    __hip_bfloat16 h = __float2bfloat16(f);
    return __builtin_bit_cast(unsigned short, h);
}
__device__ __forceinline__ float bf2f(unsigned short h) {
    union { unsigned int i; float f; } u;
    u.i = ((unsigned int)h) << 16;
    return u.f;
}

// ---------------- Kernel 1a: colnorm partials + bf16 cast --------------------
// grid.x = 4096: [tensor(2)][b(16)][cslice(32)][hwchunk(4)]. r7 shape (at the
// read ceiling); additionally writes raw bf16(x) into the u buffer so the
// rowscale pass reads half the bytes. Writes ride the (empirically separate)
// store path.
__global__ __launch_bounds__(256) void cast_colnorm_k(const float* __restrict__ ten,
                                                      const float* __restrict__ stu,
                                                      float* __restrict__ ws)
{
    int tid = threadIdx.x;
    int t   = blockIdx.x;
    if (t == 0 && tid < 32) ws[OFF_EXPS + tid] = 0.0f;  // zero accumulators

    int hwc = t & 3;
    int cs  = (t >> 2) & 31;
    int b   = (t >> 7) & 15;
    int ts  = t >> 11;                   // 0 = teacher, 1 = student
    const float* src = ts ? stu : ten;

    int hw0 = hwc * 1024 + tid * 4;
    size_t base = (size_t)b * (kC * kHW) + (size_t)cs * 8 * kHW + hw0;
    const float* p = src + base;
    unsigned short* xb = (unsigned short*)((char*)ws + OFF_U_BYTES)
                       + (size_t)ts * U_ELEMS + base;

    f32x4 v[8];
#pragma unroll
    for (int j = 0; j < 8; ++j)
        v[j] = *(const f32x4*)(p + (size_t)j * kHW);
    PIN8(v);

    f32x4 acc = {0.0f, 0.0f, 0.0f, 0.0f};
#pragma unroll
    for (int j = 0; j < 8; ++j) {
        acc[0] += v[j][0] * v[j][0];
        acc[1] += v[j][1] * v[j][1];
        acc[2] += v[j][2] * v[j][2];
        acc[3] += v[j][3] * v[j][3];
        ushort4 o;
        o.x = f2bf(v[j][0]); o.y = f2bf(v[j][1]);
        o.z = f2bf(v[j][2]); o.w = f2bf(v[j][3]);
        *(ushort4*)(xb + (size_t)j * kHW) = o;
    }

    float* part = ws + OFF_PSIM + ((size_t)(ts * 32 + cs) << 16) + b * kHW + hw0;
    *(f32x4*)part = acc;
}

// ---------------- Kernel 1b: finalize invC -----------------------------------
__global__ __launch_bounds__(256) void invc_fin_k(float* __restrict__ ws)
{
    int g0  = (blockIdx.x * 256 + threadIdx.x) * 4;   // 0..131071
    int ts  = g0 >> 16;
    int pos = g0 & 65535;

    const float* part = ws + OFF_PSIM + ((size_t)(ts * 32) << 16) + pos;
    float4 s = {0.0f, 0.0f, 0.0f, 0.0f};
#pragma unroll
    for (int q = 0; q < 4; ++q) {
        f32x4 v[8];
#pragma unroll
        for (int cs = 0; cs < 8; ++cs)
            v[cs] = *(const f32x4*)(part + ((size_t)(q * 8 + cs) << 16));
        PIN8(v);
#pragma unroll
        for (int cs = 0; cs < 8; ++cs) {
            s.x += v[cs][0]; s.y += v[cs][1]; s.z += v[cs][2]; s.w += v[cs][3];
        }
    }
    float4 o;
    o.x = 1.0f / fmaxf(sqrtf(s.x), 1e-12f);
    o.y = 1.0f / fmaxf(sqrtf(s.y), 1e-12f);
    o.z = 1.0f / fmaxf(sqrtf(s.z), 1e-12f);
    o.w = 1.0f / fmaxf(sqrtf(s.w), 1e-12f);
    *(float4*)(ws + (ts ? OFF_INVC_S : OFF_INVC_T) + pos) = o;
}

// ---------------- Kernel 2: u = xb*invC in place (bf16), row norms ----------
// One block per (b,c) row x 2 tensors. Reads 8 KB bf16 + 16 KB invC (L2-hot),
// writes 8 KB bf16 — half the read bytes of the old fp32 rownorm.
__global__ __launch_bounds__(256) void rowscale_k(float* __restrict__ ws)
{
    int tid = threadIdx.x;
    int bc  = blockIdx.x;               // b*256 + c
    int b   = bc >> 8;
    bool isT = (blockIdx.y == 0);
    unsigned short* u = (unsigned short*)((char*)ws + OFF_U_BYTES)
                      + (isT ? 0 : U_ELEMS) + (size_t)bc * kHW;
    const float* crow = ws + (isT ? OFF_INVC_T : OFF_INVC_S) + b * kHW;
    float* invD       = ws + (isT ? OFF_INVD_T : OFF_INVD_S);

    int e0 = tid * 16;
    u16x8 xa = *(const u16x8*)(u + e0);
    u16x8 xb2 = *(const u16x8*)(u + e0 + 8);
    f32x4 c[4];
#pragma unroll
    for (int q = 0; q < 4; ++q)
        c[q] = *(const f32x4*)(crow + e0 + q * 4);

    float ss = 0.0f;
    u16x8 oa, ob;
#pragma unroll
    for (int j = 0; j < 8; ++j) {
        float pa = bf2f(xa[j]) * c[j >> 2][j & 3];
        ss += pa * pa;
        oa[j] = f2bf(pa);
    }
#pragma unroll
    for (int j = 0; j < 8; ++j) {
        float pb = bf2f(xb2[j]) * c[2 + (j >> 2)][j & 3];
        ss += pb * pb;
        ob[j] = f2bf(pb);
    }
    *(u16x8*)(u + e0)     = oa;
    *(u16x8*)(u + e0 + 8) = ob;

#pragma unroll
    for (int o = 32; o; o >>= 1) ss += __shfl_down(ss, o);
    __shared__ float red[4];
    if ((tid & 63) == 0) red[tid >> 6] = ss;
    __syncthreads();
    if (tid == 0)
        invD[bc] = 1.0f / fmaxf(sqrtf(red[0] + red[1] + red[2] + red[3]), 1e-12f);
}

// ---------------- Kernel 3: batched GEMM partials (K-split) ------------------
__global__ __launch_bounds__(256) void gemm_part_k(float* __restrict__ ws,
                                                   int kIters)
{
    const unsigned short* uT = (const unsigned short*)((const char*)ws + OFF_U_BYTES);
    const unsigned short* uS = uT + U_ELEMS;
    float* psim = ws + OFF_PSIM;

    __shared__ __align__(16) unsigned short As[2][4096];
    __shared__ __align__(16) unsigned short Bs[2][4096];

    int tid = threadIdx.x;
    int bid = blockIdx.x;
    int cpx = gridDim.x >> 3;
    int w   = (bid & 7) * cpx + (bid >> 3);
    int tile = w & 15;
    int g    = w >> 4;
    int b    = g & 15;
    int kz   = g >> 4;
    int tr   = tile >> 2, tc = tile & 3;
    int lane = tid & 63, wid = tid >> 6;
    int wr   = wid >> 1, wc = wid & 1;

    int k0base = kz * (kIters * 64);

    int D0  = tid * 16;
    int r0s = D0 >> 7;
    int c0s = ((D0 & 127) ^ ((r0s & 7) << 4)) >> 1;
    int D1  = 4096 + tid * 16;
    int r1s = D1 >> 7;
    int c1s = ((D1 & 127) ^ ((r1s & 7) << 4)) >> 1;

    const unsigned short* gA = uS + ((size_t)(b * kC + tr * 64) << 12) + k0base;
    const unsigned short* gB = uT + ((size_t)(b * kC + tc * 64) << 12) + k0base;

    f32x4 acc[2][2] = {};

    GLOAD(gA + ((size_t)r0s << 12) + c0s, (char*)As[0] + D0);
    GLOAD(gA + ((size_t)r1s << 12) + c1s, (char*)As[0] + D1);
    GLOAD(gB + ((size_t)r0s << 12) + c0s, (char*)Bs[0] + D0);
    GLOAD(gB + ((size_t)r1s << 12) + c1s, (char*)Bs[0] + D1);
    __syncthreads();

    int cur = 0;
    for (int it = 0; it < kIters; ++it) {
        if (it + 1 < kIters) {
            int k0 = (it + 1) * 64;
            GLOAD(gA + ((size_t)r0s << 12) + k0 + c0s, (char*)As[cur ^ 1] + D0);
            GLOAD(gA + ((size_t)r1s << 12) + k0 + c1s, (char*)As[cur ^ 1] + D1);
            GLOAD(gB + ((size_t)r0s << 12) + k0 + c0s, (char*)Bs[cur ^ 1] + D0);
            GLOAD(gB + ((size_t)r1s << 12) + k0 + c1s, (char*)Bs[cur ^ 1] + D1);
        }
        const char* Ab = (const char*)As[cur];
        const char* Bb = (const char*)Bs[cur];
#pragma unroll
        for (int ks = 0; ks < 2; ++ks) {
            bf16x8 av[2], bv[2];
            int kb = ks * 64 + (lane >> 4) * 16;
#pragma unroll
            for (int f = 0; f < 2; ++f) {
                int row = wr * 32 + f * 16 + (lane & 15);
                av[f] = *(const bf16x8*)(Ab + (row << 7) + (kb ^ ((row & 7) << 4)));
                int col = wc * 32 + f * 16 + (lane & 15);
                bv[f] = *(const bf16x8*)(Bb + (col << 7) + (kb ^ ((col & 7) << 4)));
            }
#pragma unroll
            for (int fr = 0; fr < 2; ++fr)
#pragma unroll
                for (int fc = 0; fc < 2; ++fc)
                    acc[fr][fc] = __builtin_amdgcn_mfma_f32_16x16x32_bf16(
                        av[fr], bv[fc], acc[fr][fc], 0, 0, 0);
        }
        __syncthreads();
        cur ^= 1;
    }

    float* pt = psim + ((size_t)(kz * 16 + b) << 16);
#pragma unroll
    for (int fr = 0; fr < 2; ++fr)
#pragma unroll
        for (int fc = 0; fc < 2; ++fc) {
            int col = tc * 64 + wc * 32 + fc * 16 + (lane & 15);
#pragma unroll
            for (int j = 0; j < 4; ++j) {
                int row = tr * 64 + wr * 32 + fr * 16 + (lane >> 4) * 4 + j;
                pt[row * 256 + col] = acc[fr][fc][j];
            }
        }
}

// ---------------- Kernel 4: sum partials + scale + fused exp/diag reduce ----
__global__ __launch_bounds__(256) void reduce_k(float* __restrict__ ws, int KS)
{
    const float* psim  = ws + OFF_PSIM;
    const float* invDt = ws + OFF_INVD_T;
    const float* invDs = ws + OFF_INVD_S;

    int b     = blockIdx.x >> 6;
    int local = ((blockIdx.x & 63) << 10) + threadIdx.x * 4;   // 0..65535
    int row   = local >> 8;
    int col   = local & 255;

    float4 s = {0.0f, 0.0f, 0.0f, 0.0f};
    for (int ks = 0; ks < KS; ++ks) {
        float4 v = *(const float4*)(psim + (((size_t)(ks * 16 + b)) << 16) + local);
        s.x += v.x; s.y += v.y; s.z += v.z; s.w += v.w;
    }
    float  ds = invDs[b * 256 + row];
    float4 dt = *(const float4*)(invDt + b * 256 + col);
    float v0 = s.x * ds * dt.x;
    float v1 = s.y * ds * dt.y;
    float v2 = s.z * ds * dt.z;
    float v3 = s.w * ds * dt.w;

    float eAcc = __expf(2.0f * v0) + __expf(2.0f * v1) +
                 __expf(2.0f * v2) + __expf(2.0f * v3);
    float pAcc = 0.0f;
    if (row == col)     pAcc = v0;
    if (row == col + 1) pAcc = v1;
    if (row == col + 2) pAcc = v2;
    if (row == col + 3) pAcc = v3;

#pragma unroll
    for (int o = 32; o; o >>= 1) {
        eAcc += __shfl_down(eAcc, o);
        pAcc += __shfl_down(pAcc, o);
    }
    __shared__ float redE[4], redP[4];
    int lane = threadIdx.x & 63, wid = threadIdx.x >> 6;
    if (lane == 0) { redE[wid] = eAcc; redP[wid] = pAcc; }
    __syncthreads();
    if (threadIdx.x == 0) {
        atomicAdd(ws + OFF_EXPS + b, redE[0] + redE[1] + redE[2] + redE[3]);
        atomicAdd(ws + OFF_POSS + b, redP[0] + redP[1] + redP[2] + redP[3]);
    }
}

// ---------------- Kernel 5: finalize scalar loss -----------------------------
__global__ void finalize_k(const float* __restrict__ ws, float* __restrict__ out)
{
    if (threadIdx.x == 0) {
        const float* expSum = ws + OFF_EXPS;
        const float* posSum = ws + OFF_POSS;
        float loss = 0.0f;
        for (int b = 0; b < kB; ++b)
            loss += -2.0f * posSum[b] / (float)kC + logf(expSum[b]);
        out[0] = loss / (float)kB;
    }
}

extern "C" void kernel_launch(void* const* d_in, const int* in_sizes, int n_in,
                              void* d_out, int out_size, void* d_ws, size_t ws_size,
                              hipStream_t stream)
{
    const float* ten = (const float*)d_in[0];   // teacher_vectors
    const float* stu = (const float*)d_in[1];   // student_vectors
    float* ws  = (float*)d_ws;
    float* out = (float*)d_out;

    int KS = 4;
    {
        size_t base = OFF_PSIM * 4ull;
        if (ws_size < base + 4ull * 16 * 65536 * 4) KS = 2;
        if (ws_size < base + 2ull * 16 * 65536 * 4) KS = 1;
    }
    int kIters = (kHW / KS) / 64;

    cast_colnorm_k<<<dim3(4096), 256, 0, stream>>>(ten, stu, ws);
    invc_fin_k<<<dim3(128), 256, 0, stream>>>(ws);
    rowscale_k<<<dim3(4096, 2), 256, 0, stream>>>(ws);
    gemm_part_k<<<dim3(256 * KS), 256, 0, stream>>>(ws, kIters);
    reduce_k<<<dim3(1024), 256, 0, stream>>>(ws, KS);
    finalize_k<<<1, 64, 0, stream>>>(ws, out);
}

// Round 9
// 92.426 us; speedup vs baseline: 1.0873x; 1.0873x over previous
//
#include <hip/hip_runtime.h>
#include <hip/hip_bf16.h>

typedef short bf16x8 __attribute__((ext_vector_type(8)));
typedef float f32x4 __attribute__((ext_vector_type(4)));
typedef unsigned short u16x8 __attribute__((ext_vector_type(8)));

#define GLOAD(gp, lp)                                                          \
    __builtin_amdgcn_global_load_lds(                                          \
        (const __attribute__((address_space(1))) void*)(gp),                   \
        (__attribute__((address_space(3))) void*)(lp), 16, 0, 0)

#define PIN8(v)                                                                \
    asm volatile("" ::"v"((v)[0]), "v"((v)[1]), "v"((v)[2]), "v"((v)[3]),      \
                 "v"((v)[4]), "v"((v)[5]), "v"((v)[6]), "v"((v)[7]))

// Problem sizes: B=16, C=256, HW=4096 (64*64)
static constexpr int kB = 16;
static constexpr int kC = 256;
static constexpr int kHW = 4096;

// Workspace layout (float offsets)
static constexpr int OFF_INVC_T = 0;        // 65536 floats
static constexpr int OFF_INVC_S = 65536;    // 65536 floats
static constexpr int OFF_INVD_T = 131072;   // 4096 floats
static constexpr int OFF_INVD_S = 135168;   // 4096 floats
static constexpr int OFF_EXPS   = 139264;   // 16 floats
static constexpr int OFF_POSS   = 139280;   // 16 floats
// bf16 area: teacher raw xb_t (GEMM B operand), then student (raw, overwritten
// in place by u_s = xb_s*invCs*invCt, the GEMM A operand).
static constexpr size_t OFF_U_BYTES = 139296ull * 4ull;
static constexpr size_t U_ELEMS = (size_t)kB * kC * kHW;      // 16777216 per tensor
// psim area after u. Aliased earlier by colnorm partials (64 x 65536 floats
// = 16 MB fp32), consumed by invc_fin_k, then overwritten by gemm partial
// tiles in BF16 (KS*16*65536*2 B <= 8 MB).
static constexpr size_t OFF_PSIM = 139296ull + 16777216ull;   // float offset

__device__ __forceinline__ unsigned short f2bf(float f) {
    __hip_bfloat16 h = __float2bfloat16(f);
    return __builtin_bit_cast(unsigned short, h);
}
__device__ __forceinline__ float bf2f(unsigned short h) {
    union { unsigned int i; float f; } u;
    u.i = ((unsigned int)h) << 16;
    return u.f;
}

// ---------------- Kernel 1a: colnorm partials + bf16 cast --------------------
// grid.x = 4096: [tensor(2)][b(16)][cslice(32)][hwchunk(4)]. At the measured
// first-touch combined ceiling (~3.9 TB/s); R 134 MB + W 80 MB.
__global__ __launch_bounds__(256) void cast_colnorm_k(const float* __restrict__ ten,
                                                      const float* __restrict__ stu,
                                                      float* __restrict__ ws)
{
    int tid = threadIdx.x;
    int t   = blockIdx.x;
    if (t == 0 && tid < 32) ws[OFF_EXPS + tid] = 0.0f;  // zero accumulators

    int hwc = t & 3;
    int cs  = (t >> 2) & 31;
    int b   = (t >> 7) & 15;
    int ts  = t >> 11;                   // 0 = teacher, 1 = student
    const float* src = ts ? stu : ten;

    int hw0 = hwc * 1024 + tid * 4;
    size_t base = (size_t)b * (kC * kHW) + (size_t)cs * 8 * kHW + hw0;
    const float* p = src + base;
    unsigned short* xb = (unsigned short*)((char*)ws + OFF_U_BYTES)
                       + (size_t)ts * U_ELEMS + base;

    f32x4 v[8];
#pragma unroll
    for (int j = 0; j < 8; ++j)
        v[j] = *(const f32x4*)(p + (size_t)j * kHW);
    PIN8(v);

    f32x4 acc = {0.0f, 0.0f, 0.0f, 0.0f};
#pragma unroll
    for (int j = 0; j < 8; ++j) {
        acc[0] += v[j][0] * v[j][0];
        acc[1] += v[j][1] * v[j][1];
        acc[2] += v[j][2] * v[j][2];
        acc[3] += v[j][3] * v[j][3];
        ushort4 o;
        o.x = f2bf(v[j][0]); o.y = f2bf(v[j][1]);
        o.z = f2bf(v[j][2]); o.w = f2bf(v[j][3]);
        *(ushort4*)(xb + (size_t)j * kHW) = o;
    }

    float* part = ws + OFF_PSIM + ((size_t)(ts * 32 + cs) << 16) + b * kHW + hw0;
    *(f32x4*)part = acc;
}

// ---------------- Kernel 1b: finalize invC -----------------------------------
__global__ __launch_bounds__(256) void invc_fin_k(float* __restrict__ ws)
{
    int g0  = (blockIdx.x * 256 + threadIdx.x) * 4;   // 0..131071
    int ts  = g0 >> 16;
    int pos = g0 & 65535;

    const float* part = ws + OFF_PSIM + ((size_t)(ts * 32) << 16) + pos;
    float4 s = {0.0f, 0.0f, 0.0f, 0.0f};
#pragma unroll
    for (int q = 0; q < 4; ++q) {
        f32x4 v[8];
#pragma unroll
        for (int cs = 0; cs < 8; ++cs)
            v[cs] = *(const f32x4*)(part + ((size_t)(q * 8 + cs) << 16));
        PIN8(v);
#pragma unroll
        for (int cs = 0; cs < 8; ++cs) {
            s.x += v[cs][0]; s.y += v[cs][1]; s.z += v[cs][2]; s.w += v[cs][3];
        }
    }
    float4 o;
    o.x = 1.0f / fmaxf(sqrtf(s.x), 1e-12f);
    o.y = 1.0f / fmaxf(sqrtf(s.y), 1e-12f);
    o.z = 1.0f / fmaxf(sqrtf(s.z), 1e-12f);
    o.w = 1.0f / fmaxf(sqrtf(s.w), 1e-12f);
    *(float4*)(ws + (ts ? OFF_INVC_S : OFF_INVC_T) + pos) = o;
}

// ---------------- Kernel 2: row norms; student also scaled in place ---------
// y=0 teacher: read xb_t, compute invD_t = 1/||xb_t*invCt||, NO write.
// y=1 student: read xb_s, invD_s = 1/||xb_s*invCs||, write u_s = xb_s*invCs*invCt.
__global__ __launch_bounds__(256) void rowscale_k(float* __restrict__ ws)
{
    int tid = threadIdx.x;
    int bc  = blockIdx.x;               // b*256 + c
    int b   = bc >> 8;
    bool isT = (blockIdx.y == 0);
    unsigned short* u = (unsigned short*)((char*)ws + OFF_U_BYTES)
                      + (isT ? 0 : U_ELEMS) + (size_t)bc * kHW;
    const float* cOwn = ws + (isT ? OFF_INVC_T : OFF_INVC_S) + b * kHW;
    const float* cT   = ws + OFF_INVC_T + b * kHW;
    float* invD       = ws + (isT ? OFF_INVD_T : OFF_INVD_S);

    int e0 = tid * 16;
    u16x8 xa  = *(const u16x8*)(u + e0);
    u16x8 xb2 = *(const u16x8*)(u + e0 + 8);
    f32x4 c[4];
#pragma unroll
    for (int q = 0; q < 4; ++q)
        c[q] = *(const f32x4*)(cOwn + e0 + q * 4);

    float ss = 0.0f;
    if (isT) {
#pragma unroll
        for (int j = 0; j < 8; ++j) {
            float pa = bf2f(xa[j]) * c[j >> 2][j & 3];
            ss += pa * pa;
        }
#pragma unroll
        for (int j = 0; j < 8; ++j) {
            float pb = bf2f(xb2[j]) * c[2 + (j >> 2)][j & 3];
            ss += pb * pb;
        }
    } else {
        f32x4 ct[4];
#pragma unroll
        for (int q = 0; q < 4; ++q)
            ct[q] = *(const f32x4*)(cT + e0 + q * 4);
        u16x8 oa, ob;
#pragma unroll
        for (int j = 0; j < 8; ++j) {
            float pa = bf2f(xa[j]) * c[j >> 2][j & 3];
            ss += pa * pa;
            oa[j] = f2bf(pa * ct[j >> 2][j & 3]);
        }
#pragma unroll
        for (int j = 0; j < 8; ++j) {
            float pb = bf2f(xb2[j]) * c[2 + (j >> 2)][j & 3];
            ss += pb * pb;
            ob[j] = f2bf(pb * ct[2 + (j >> 2)][j & 3]);
        }
        *(u16x8*)(u + e0)     = oa;
        *(u16x8*)(u + e0 + 8) = ob;
    }

#pragma unroll
    for (int o = 32; o; o >>= 1) ss += __shfl_down(ss, o);
    __shared__ float red[4];
    if ((tid & 63) == 0) red[tid >> 6] = ss;
    __syncthreads();
    if (tid == 0)
        invD[bc] = 1.0f / fmaxf(sqrtf(red[0] + red[1] + red[2] + red[3]), 1e-12f);
}

// ---------------- Kernel 3: batched GEMM partials (K-split, bf16 psim) -------
__global__ __launch_bounds__(256) void gemm_part_k(float* __restrict__ ws,
                                                   int kIters)
{
    const unsigned short* uT = (const unsigned short*)((const char*)ws + OFF_U_BYTES);
    const unsigned short* uS = uT + U_ELEMS;

    __shared__ __align__(16) unsigned short As[2][4096];
    __shared__ __align__(16) unsigned short Bs[2][4096];

    int tid = threadIdx.x;
    int bid = blockIdx.x;
    int cpx = gridDim.x >> 3;
    int w   = (bid & 7) * cpx + (bid >> 3);
    int tile = w & 15;
    int g    = w >> 4;
    int b    = g & 15;
    int kz   = g >> 4;
    int tr   = tile >> 2, tc = tile & 3;
    int lane = tid & 63, wid = tid >> 6;
    int wr   = wid >> 1, wc = wid & 1;

    int k0base = kz * (kIters * 64);

    int D0  = tid * 16;
    int r0s = D0 >> 7;
    int c0s = ((D0 & 127) ^ ((r0s & 7) << 4)) >> 1;
    int D1  = 4096 + tid * 16;
    int r1s = D1 >> 7;
    int c1s = ((D1 & 127) ^ ((r1s & 7) << 4)) >> 1;

    const unsigned short* gA = uS + ((size_t)(b * kC + tr * 64) << 12) + k0base;
    const unsigned short* gB = uT + ((size_t)(b * kC + tc * 64) << 12) + k0base;

    f32x4 acc[2][2] = {};

    GLOAD(gA + ((size_t)r0s << 12) + c0s, (char*)As[0] + D0);
    GLOAD(gA + ((size_t)r1s << 12) + c1s, (char*)As[0] + D1);
    GLOAD(gB + ((size_t)r0s << 12) + c0s, (char*)Bs[0] + D0);
    GLOAD(gB + ((size_t)r1s << 12) + c1s, (char*)Bs[0] + D1);
    __syncthreads();

    int cur = 0;
    for (int it = 0; it < kIters; ++it) {
        if (it + 1 < kIters) {
            int k0 = (it + 1) * 64;
            GLOAD(gA + ((size_t)r0s << 12) + k0 + c0s, (char*)As[cur ^ 1] + D0);
            GLOAD(gA + ((size_t)r1s << 12) + k0 + c1s, (char*)As[cur ^ 1] + D1);
            GLOAD(gB + ((size_t)r0s << 12) + k0 + c0s, (char*)Bs[cur ^ 1] + D0);
            GLOAD(gB + ((size_t)r1s << 12) + k0 + c1s, (char*)Bs[cur ^ 1] + D1);
        }
        const char* Ab = (const char*)As[cur];
        const char* Bb = (const char*)Bs[cur];
#pragma unroll
        for (int ks = 0; ks < 2; ++ks) {
            bf16x8 av[2], bv[2];
            int kb = ks * 64 + (lane >> 4) * 16;
#pragma unroll
            for (int f = 0; f < 2; ++f) {
                int row = wr * 32 + f * 16 + (lane & 15);
                av[f] = *(const bf16x8*)(Ab + (row << 7) + (kb ^ ((row & 7) << 4)));
                int col = wc * 32 + f * 16 + (lane & 15);
                bv[f] = *(const bf16x8*)(Bb + (col << 7) + (kb ^ ((col & 7) << 4)));
            }
#pragma unroll
            for (int fr = 0; fr < 2; ++fr)
#pragma unroll
                for (int fc = 0; fc < 2; ++fc)
                    acc[fr][fc] = __builtin_amdgcn_mfma_f32_16x16x32_bf16(
                        av[fr], bv[fc], acc[fr][fc], 0, 0, 0);
        }
        __syncthreads();
        cur ^= 1;
    }

    // bf16 partial tile (halves psim traffic; |partial| <= ~4 -> err ~1e-3)
    unsigned short* pt = (unsigned short*)(ws + OFF_PSIM)
                       + ((size_t)(kz * 16 + b) << 16);
#pragma unroll
    for (int fr = 0; fr < 2; ++fr)
#pragma unroll
        for (int fc = 0; fc < 2; ++fc) {
            int col = tc * 64 + wc * 32 + fc * 16 + (lane & 15);
#pragma unroll
            for (int j = 0; j < 4; ++j) {
                int row = tr * 64 + wr * 32 + fr * 16 + (lane >> 4) * 4 + j;
                pt[row * 256 + col] = f2bf(acc[fr][fc][j]);
            }
        }
}

// ---------------- Kernel 4: sum bf16 partials + scale + exp/diag reduce -----
__global__ __launch_bounds__(256) void reduce_k(float* __restrict__ ws, int KS)
{
    const unsigned short* psim = (const unsigned short*)(ws + OFF_PSIM);
    const float* invDt = ws + OFF_INVD_T;
    const float* invDs = ws + OFF_INVD_S;

    int b     = blockIdx.x >> 5;                               // 512 blocks
    int local = ((blockIdx.x & 31) << 11) + threadIdx.x * 8;   // 0..65535
    int row   = local >> 8;
    int col   = local & 255;

    float s[8] = {0, 0, 0, 0, 0, 0, 0, 0};
    for (int ks = 0; ks < KS; ++ks) {
        u16x8 v = *(const u16x8*)(psim + (((size_t)(ks * 16 + b)) << 16) + local);
#pragma unroll
        for (int j = 0; j < 8; ++j) s[j] += bf2f(v[j]);
    }
    float  ds  = invDs[b * 256 + row];
    f32x4  dt0 = *(const f32x4*)(invDt + b * 256 + col);
    f32x4  dt1 = *(const f32x4*)(invDt + b * 256 + col + 4);

    float eAcc = 0.0f, pAcc = 0.0f;
#pragma unroll
    for (int j = 0; j < 8; ++j) {
        float dt = (j < 4) ? dt0[j] : dt1[j - 4];
        float v  = s[j] * ds * dt;
        eAcc += __expf(2.0f * v);                              // 1/T = 2
        if (row == col + j) pAcc = v;
    }

#pragma unroll
    for (int o = 32; o; o >>= 1) {
        eAcc += __shfl_down(eAcc, o);
        pAcc += __shfl_down(pAcc, o);
    }
    __shared__ float redE[4], redP[4];
    int lane = threadIdx.x & 63, wid = threadIdx.x >> 6;
    if (lane == 0) { redE[wid] = eAcc; redP[wid] = pAcc; }
    __syncthreads();
    if (threadIdx.x == 0) {
        atomicAdd(ws + OFF_EXPS + b, redE[0] + redE[1] + redE[2] + redE[3]);
        atomicAdd(ws + OFF_POSS + b, redP[0] + redP[1] + redP[2] + redP[3]);
    }
}

// ---------------- Kernel 5: finalize scalar loss -----------------------------
__global__ void finalize_k(const float* __restrict__ ws, float* __restrict__ out)
{
    if (threadIdx.x == 0) {
        const float* expSum = ws + OFF_EXPS;
        const float* posSum = ws + OFF_POSS;
        float loss = 0.0f;
        for (int b = 0; b < kB; ++b)
            loss += -2.0f * posSum[b] / (float)kC + logf(expSum[b]);
        out[0] = loss / (float)kB;
    }
}

extern "C" void kernel_launch(void* const* d_in, const int* in_sizes, int n_in,
                              void* d_out, int out_size, void* d_ws, size_t ws_size,
                              hipStream_t stream)
{
    const float* ten = (const float*)d_in[0];   // teacher_vectors
    const float* stu = (const float*)d_in[1];   // student_vectors
    float* ws  = (float*)d_ws;
    float* out = (float*)d_out;

    // Colnorm partials need 16 MB at OFF_PSIM (dominates bf16 psim, <=8 MB).
    int KS = 4;
    {
        size_t base = OFF_PSIM * 4ull;
        if (ws_size < base + 16ull * 1024 * 1024) KS = 2;  // (kept for safety)
    }
    int kIters = (kHW / KS) / 64;

    cast_colnorm_k<<<dim3(4096), 256, 0, stream>>>(ten, stu, ws);
    invc_fin_k<<<dim3(128), 256, 0, stream>>>(ws);
    rowscale_k<<<dim3(4096, 2), 256, 0, stream>>>(ws);
    gemm_part_k<<<dim3(256 * KS), 256, 0, stream>>>(ws, kIters);
    reduce_k<<<dim3(512), 256, 0, stream>>>(ws, KS);
    finalize_k<<<1, 64, 0, stream>>>(ws, out);
}

// Round 10
// 88.920 us; speedup vs baseline: 1.1301x; 1.0394x over previous
//
#include <hip/hip_runtime.h>
#include <hip/hip_bf16.h>

typedef short bf16x8 __attribute__((ext_vector_type(8)));
typedef float f32x4 __attribute__((ext_vector_type(4)));
typedef unsigned short u16x8 __attribute__((ext_vector_type(8)));

#define GLOAD(gp, lp)                                                          \
    __builtin_amdgcn_global_load_lds(                                          \
        (const __attribute__((address_space(1))) void*)(gp),                   \
        (__attribute__((address_space(3))) void*)(lp), 16, 0, 0)

#define PIN8(v)                                                                \
    asm volatile("" ::"v"((v)[0]), "v"((v)[1]), "v"((v)[2]), "v"((v)[3]),      \
                 "v"((v)[4]), "v"((v)[5]), "v"((v)[6]), "v"((v)[7]))

// Problem sizes: B=16, C=256, HW=4096 (64*64)
static constexpr int kB = 16;
static constexpr int kC = 256;
static constexpr int kHW = 4096;

// Workspace layout (float offsets)
static constexpr int OFF_INVC_T = 0;        // 65536 floats
static constexpr int OFF_INVC_S = 65536;    // 65536 floats
static constexpr int OFF_INVD_T = 131072;   // 4096 floats
static constexpr int OFF_INVD_S = 135168;   // 4096 floats
static constexpr int OFF_EXPS   = 139264;   // 16 floats
static constexpr int OFF_POSS   = 139280;   // 16 floats
// bf16 area: teacher raw xb_t (GEMM B operand), then student (raw, overwritten
// in place by u_s = xb_s*invCs*invCt, the GEMM A operand).
static constexpr size_t OFF_U_BYTES = 139296ull * 4ull;
static constexpr size_t U_ELEMS = (size_t)kB * kC * kHW;      // 16777216 per tensor
// psim area after u. Aliased earlier by colnorm partials (16 x 65536 floats
// = 4 MB fp32), consumed by invc_fin_k, then overwritten by gemm partial
// tiles in BF16 (KS*16*65536*2 B <= 8 MB).
static constexpr size_t OFF_PSIM = 139296ull + 16777216ull;   // float offset

__device__ __forceinline__ unsigned short f2bf(float f) {
    __hip_bfloat16 h = __float2bfloat16(f);
    return __builtin_bit_cast(unsigned short, h);
}
__device__ __forceinline__ float bf2f(unsigned short h) {
    union { unsigned int i; float f; } u;
    u.i = ((unsigned int)h) << 16;
    return u.f;
}

// ---------------- Kernel 1a: colnorm partials + bf16 cast --------------------
// grid.x = 512: [tensor(2)][b(16)][cslice(8)][hwchunk(2)]. Thread owns 8
// CONTIGUOUS hw -> full-width 16 B bf16 stores (was 8 B ushort4). 32 channels
// per block in 4 pinned batches of 8; partials: 16 slices (4 MB).
__global__ __launch_bounds__(256) void cast_colnorm_k(const float* __restrict__ ten,
                                                      const float* __restrict__ stu,
                                                      float* __restrict__ ws)
{
    int tid = threadIdx.x;
    int t   = blockIdx.x;
    if (t == 0 && tid < 32) ws[OFF_EXPS + tid] = 0.0f;  // zero accumulators

    int hwc = t & 1;
    int cs  = (t >> 1) & 7;
    int b   = (t >> 4) & 15;
    int ts  = t >> 8;                    // 0 = teacher, 1 = student
    const float* src = ts ? stu : ten;

    int hw0 = hwc * 2048 + tid * 8;
    size_t base = (size_t)b * (kC * kHW) + (size_t)cs * 32 * kHW + hw0;
    const float* p = src + base;
    unsigned short* xb = (unsigned short*)((char*)ws + OFF_U_BYTES)
                       + (size_t)ts * U_ELEMS + base;

    f32x4 acc0 = {0.0f, 0.0f, 0.0f, 0.0f};
    f32x4 acc1 = {0.0f, 0.0f, 0.0f, 0.0f};

#pragma unroll
    for (int g = 0; g < 4; ++g) {
        const float* q = p + (size_t)g * 8 * kHW;
        f32x4 v[16];
#pragma unroll
        for (int j = 0; j < 8; ++j) {
            v[2 * j]     = *(const f32x4*)(q + (size_t)j * kHW);
            v[2 * j + 1] = *(const f32x4*)(q + (size_t)j * kHW + 4);
        }
        PIN8(v);
        PIN8((v + 8));
#pragma unroll
        for (int j = 0; j < 8; ++j) {
            f32x4 a = v[2 * j], c = v[2 * j + 1];
            acc0[0] += a[0] * a[0]; acc0[1] += a[1] * a[1];
            acc0[2] += a[2] * a[2]; acc0[3] += a[3] * a[3];
            acc1[0] += c[0] * c[0]; acc1[1] += c[1] * c[1];
            acc1[2] += c[2] * c[2]; acc1[3] += c[3] * c[3];
            u16x8 o;
            o[0] = f2bf(a[0]); o[1] = f2bf(a[1]); o[2] = f2bf(a[2]); o[3] = f2bf(a[3]);
            o[4] = f2bf(c[0]); o[5] = f2bf(c[1]); o[6] = f2bf(c[2]); o[7] = f2bf(c[3]);
            *(u16x8*)(xb + (size_t)(g * 8 + j) * kHW) = o;   // 16 B store
        }
    }

    // partial[slice = ts*8+cs][b*4096 + hw0], 32 B contiguous per thread
    float* part = ws + OFF_PSIM + ((size_t)(ts * 8 + cs) << 16) + b * kHW + hw0;
    *(f32x4*)part       = acc0;
    *(f32x4*)(part + 4) = acc1;
}

// ---------------- Kernel 1b: finalize invC (16 slices) -----------------------
__global__ __launch_bounds__(256) void invc_fin_k(float* __restrict__ ws)
{
    int g0  = (blockIdx.x * 256 + threadIdx.x) * 4;   // 0..131071
    int ts  = g0 >> 16;
    int pos = g0 & 65535;

    const float* part = ws + OFF_PSIM + ((size_t)(ts * 8) << 16) + pos;
    f32x4 v[8];
#pragma unroll
    for (int cs = 0; cs < 8; ++cs)
        v[cs] = *(const f32x4*)(part + ((size_t)cs << 16));
    PIN8(v);
    float4 s = {0.0f, 0.0f, 0.0f, 0.0f};
#pragma unroll
    for (int cs = 0; cs < 8; ++cs) {
        s.x += v[cs][0]; s.y += v[cs][1]; s.z += v[cs][2]; s.w += v[cs][3];
    }
    float4 o;
    o.x = 1.0f / fmaxf(sqrtf(s.x), 1e-12f);
    o.y = 1.0f / fmaxf(sqrtf(s.y), 1e-12f);
    o.z = 1.0f / fmaxf(sqrtf(s.z), 1e-12f);
    o.w = 1.0f / fmaxf(sqrtf(s.w), 1e-12f);
    *(float4*)(ws + (ts ? OFF_INVC_S : OFF_INVC_T) + pos) = o;
}

// ---------------- Kernel 2: row norms; student also scaled in place ---------
// y=0 teacher: read xb_t, invD_t = 1/||xb_t*invCt||, NO write.
// y=1 student: read xb_s, invD_s = 1/||xb_s*invCs||, write u_s = xb_s*invCs*invCt.
__global__ __launch_bounds__(256) void rowscale_k(float* __restrict__ ws)
{
    int tid = threadIdx.x;
    int bc  = blockIdx.x;               // b*256 + c
    int b   = bc >> 8;
    bool isT = (blockIdx.y == 0);
    unsigned short* u = (unsigned short*)((char*)ws + OFF_U_BYTES)
                      + (isT ? 0 : U_ELEMS) + (size_t)bc * kHW;
    const float* cOwn = ws + (isT ? OFF_INVC_T : OFF_INVC_S) + b * kHW;
    const float* cT   = ws + OFF_INVC_T + b * kHW;
    float* invD       = ws + (isT ? OFF_INVD_T : OFF_INVD_S);

    int e0 = tid * 16;
    u16x8 xa  = *(const u16x8*)(u + e0);
    u16x8 xb2 = *(const u16x8*)(u + e0 + 8);
    f32x4 c[4];
#pragma unroll
    for (int q = 0; q < 4; ++q)
        c[q] = *(const f32x4*)(cOwn + e0 + q * 4);

    float ss = 0.0f;
    if (isT) {
#pragma unroll
        for (int j = 0; j < 8; ++j) {
            float pa = bf2f(xa[j]) * c[j >> 2][j & 3];
            ss += pa * pa;
        }
#pragma unroll
        for (int j = 0; j < 8; ++j) {
            float pb = bf2f(xb2[j]) * c[2 + (j >> 2)][j & 3];
            ss += pb * pb;
        }
    } else {
        f32x4 ct[4];
#pragma unroll
        for (int q = 0; q < 4; ++q)
            ct[q] = *(const f32x4*)(cT + e0 + q * 4);
        u16x8 oa, ob;
#pragma unroll
        for (int j = 0; j < 8; ++j) {
            float pa = bf2f(xa[j]) * c[j >> 2][j & 3];
            ss += pa * pa;
            oa[j] = f2bf(pa * ct[j >> 2][j & 3]);
        }
#pragma unroll
        for (int j = 0; j < 8; ++j) {
            float pb = bf2f(xb2[j]) * c[2 + (j >> 2)][j & 3];
            ss += pb * pb;
            ob[j] = f2bf(pb * ct[2 + (j >> 2)][j & 3]);
        }
        *(u16x8*)(u + e0)     = oa;
        *(u16x8*)(u + e0 + 8) = ob;
    }

#pragma unroll
    for (int o = 32; o; o >>= 1) ss += __shfl_down(ss, o);
    __shared__ float red[4];
    if ((tid & 63) == 0) red[tid >> 6] = ss;
    __syncthreads();
    if (tid == 0)
        invD[bc] = 1.0f / fmaxf(sqrtf(red[0] + red[1] + red[2] + red[3]), 1e-12f);
}

// ---------------- Kernel 3: batched GEMM partials (K-split, bf16 psim) -------
__global__ __launch_bounds__(256) void gemm_part_k(float* __restrict__ ws,
                                                   int kIters)
{
    const unsigned short* uT = (const unsigned short*)((const char*)ws + OFF_U_BYTES);
    const unsigned short* uS = uT + U_ELEMS;

    __shared__ __align__(16) unsigned short As[2][4096];
    __shared__ __align__(16) unsigned short Bs[2][4096];

    int tid = threadIdx.x;
    int bid = blockIdx.x;
    int cpx = gridDim.x >> 3;
    int w   = (bid & 7) * cpx + (bid >> 3);
    int tile = w & 15;
    int g    = w >> 4;
    int b    = g & 15;
    int kz   = g >> 4;
    int tr   = tile >> 2, tc = tile & 3;
    int lane = tid & 63, wid = tid >> 6;
    int wr   = wid >> 1, wc = wid & 1;

    int k0base = kz * (kIters * 64);

    int D0  = tid * 16;
    int r0s = D0 >> 7;
    int c0s = ((D0 & 127) ^ ((r0s & 7) << 4)) >> 1;
    int D1  = 4096 + tid * 16;
    int r1s = D1 >> 7;
    int c1s = ((D1 & 127) ^ ((r1s & 7) << 4)) >> 1;

    const unsigned short* gA = uS + ((size_t)(b * kC + tr * 64) << 12) + k0base;
    const unsigned short* gB = uT + ((size_t)(b * kC + tc * 64) << 12) + k0base;

    f32x4 acc[2][2] = {};

    GLOAD(gA + ((size_t)r0s << 12) + c0s, (char*)As[0] + D0);
    GLOAD(gA + ((size_t)r1s << 12) + c1s, (char*)As[0] + D1);
    GLOAD(gB + ((size_t)r0s << 12) + c0s, (char*)Bs[0] + D0);
    GLOAD(gB + ((size_t)r1s << 12) + c1s, (char*)Bs[0] + D1);
    __syncthreads();

    int cur = 0;
    for (int it = 0; it < kIters; ++it) {
        if (it + 1 < kIters) {
            int k0 = (it + 1) * 64;
            GLOAD(gA + ((size_t)r0s << 12) + k0 + c0s, (char*)As[cur ^ 1] + D0);
            GLOAD(gA + ((size_t)r1s << 12) + k0 + c1s, (char*)As[cur ^ 1] + D1);
            GLOAD(gB + ((size_t)r0s << 12) + k0 + c0s, (char*)Bs[cur ^ 1] + D0);
            GLOAD(gB + ((size_t)r1s << 12) + k0 + c1s, (char*)Bs[cur ^ 1] + D1);
        }
        const char* Ab = (const char*)As[cur];
        const char* Bb = (const char*)Bs[cur];
#pragma unroll
        for (int ks = 0; ks < 2; ++ks) {
            bf16x8 av[2], bv[2];
            int kb = ks * 64 + (lane >> 4) * 16;
#pragma unroll
            for (int f = 0; f < 2; ++f) {
                int row = wr * 32 + f * 16 + (lane & 15);
                av[f] = *(const bf16x8*)(Ab + (row << 7) + (kb ^ ((row & 7) << 4)));
                int col = wc * 32 + f * 16 + (lane & 15);
                bv[f] = *(const bf16x8*)(Bb + (col << 7) + (kb ^ ((col & 7) << 4)));
            }
#pragma unroll
            for (int fr = 0; fr < 2; ++fr)
#pragma unroll
                for (int fc = 0; fc < 2; ++fc)
                    acc[fr][fc] = __builtin_amdgcn_mfma_f32_16x16x32_bf16(
                        av[fr], bv[fc], acc[fr][fc], 0, 0, 0);
        }
        __syncthreads();
        cur ^= 1;
    }

    // bf16 partial tile (|partial| <= ~4 -> err ~1e-3)
    unsigned short* pt = (unsigned short*)(ws + OFF_PSIM)
                       + ((size_t)(kz * 16 + b) << 16);
#pragma unroll
    for (int fr = 0; fr < 2; ++fr)
#pragma unroll
        for (int fc = 0; fc < 2; ++fc) {
            int col = tc * 64 + wc * 32 + fc * 16 + (lane & 15);
#pragma unroll
            for (int j = 0; j < 4; ++j) {
                int row = tr * 64 + wr * 32 + fr * 16 + (lane >> 4) * 4 + j;
                pt[row * 256 + col] = f2bf(acc[fr][fc][j]);
            }
        }
}

// ---------------- Kernel 4: sum bf16 partials + scale + exp/diag reduce -----
__global__ __launch_bounds__(256) void reduce_k(float* __restrict__ ws, int KS)
{
    const unsigned short* psim = (const unsigned short*)(ws + OFF_PSIM);
    const float* invDt = ws + OFF_INVD_T;
    const float* invDs = ws + OFF_INVD_S;

    int b     = blockIdx.x >> 5;                               // 512 blocks
    int local = ((blockIdx.x & 31) << 11) + threadIdx.x * 8;   // 0..65535
    int row   = local >> 8;
    int col   = local & 255;

    float s[8] = {0, 0, 0, 0, 0, 0, 0, 0};
    for (int ks = 0; ks < KS; ++ks) {
        u16x8 v = *(const u16x8*)(psim + (((size_t)(ks * 16 + b)) << 16) + local);
#pragma unroll
        for (int j = 0; j < 8; ++j) s[j] += bf2f(v[j]);
    }
    float  ds  = invDs[b * 256 + row];
    f32x4  dt0 = *(const f32x4*)(invDt + b * 256 + col);
    f32x4  dt1 = *(const f32x4*)(invDt + b * 256 + col + 4);

    float eAcc = 0.0f, pAcc = 0.0f;
#pragma unroll
    for (int j = 0; j < 8; ++j) {
        float dt = (j < 4) ? dt0[j] : dt1[j - 4];
        float v  = s[j] * ds * dt;
        eAcc += __expf(2.0f * v);                              // 1/T = 2
        if (row == col + j) pAcc = v;
    }

#pragma unroll
    for (int o = 32; o; o >>= 1) {
        eAcc += __shfl_down(eAcc, o);
        pAcc += __shfl_down(pAcc, o);
    }
    __shared__ float redE[4], redP[4];
    int lane = threadIdx.x & 63, wid = threadIdx.x >> 6;
    if (lane == 0) { redE[wid] = eAcc; redP[wid] = pAcc; }
    __syncthreads();
    if (threadIdx.x == 0) {
        atomicAdd(ws + OFF_EXPS + b, redE[0] + redE[1] + redE[2] + redE[3]);
        atomicAdd(ws + OFF_POSS + b, redP[0] + redP[1] + redP[2] + redP[3]);
    }
}

// ---------------- Kernel 5: finalize scalar loss -----------------------------
__global__ void finalize_k(const float* __restrict__ ws, float* __restrict__ out)
{
    if (threadIdx.x == 0) {
        const float* expSum = ws + OFF_EXPS;
        const float* posSum = ws + OFF_POSS;
        float loss = 0.0f;
        for (int b = 0; b < kB; ++b)
            loss += -2.0f * posSum[b] / (float)kC + logf(expSum[b]);
        out[0] = loss / (float)kB;
    }
}

extern "C" void kernel_launch(void* const* d_in, const int* in_sizes, int n_in,
                              void* d_out, int out_size, void* d_ws, size_t ws_size,
                              hipStream_t stream)
{
    const float* ten = (const float*)d_in[0];   // teacher_vectors
    const float* stu = (const float*)d_in[1];   // student_vectors
    float* ws  = (float*)d_ws;
    float* out = (float*)d_out;

    int KS = 4;
    {
        size_t base = OFF_PSIM * 4ull;
        if (ws_size < base + 16ull * 1024 * 1024) KS = 2;  // safety
    }
    int kIters = (kHW / KS) / 64;

    cast_colnorm_k<<<dim3(512), 256, 0, stream>>>(ten, stu, ws);
    invc_fin_k<<<dim3(128), 256, 0, stream>>>(ws);
    rowscale_k<<<dim3(4096, 2), 256, 0, stream>>>(ws);
    gemm_part_k<<<dim3(256 * KS), 256, 0, stream>>>(ws, kIters);
    reduce_k<<<dim3(512), 256, 0, stream>>>(ws, KS);
    finalize_k<<<1, 64, 0, stream>>>(ws, out);
}